// Round 2
// baseline (228.897 us; speedup 1.0000x reference)
//
#include <hip/hip_runtime.h>
#include <hip/hip_bf16.h>

#define BB 4
#define NN 200
#define HH 300
#define KS 10   // k-steps of 32 (K padded to 320)
#define GF 19   // g-frags of 16 (G padded to 304)
#define ALD 328 // A LDS row stride in bf16 (656 B: 16B-aligned, 2-way-free banks)

typedef __attribute__((ext_vector_type(8))) short short8;
typedef __attribute__((ext_vector_type(4))) float float4v;

static __device__ __forceinline__ ushort f2bf(float x) {
    union { float f; uint u; } v; v.f = x;
    uint r = v.u + 0x7FFFu + ((v.u >> 16) & 1u);  // RNE
    return (ushort)(r >> 16);
}

// Pack U_w (g,h) f32 -> bf16 in MFMA B-fragment order:
// Bp[((ks*GF+gf)*64 + lane)*8 + j] = Uw[g= gf*16+(lane&15)][h= ks*32+(lane>>4)*8+j], 0 if OOB
__global__ void pack_u(const float* __restrict__ Uw, ushort* __restrict__ Bp) {
    int idx = blockIdx.x * 256 + threadIdx.x;
    if (idx >= KS * GF * 64) return;
    int lane = idx & 63;
    int kg = idx >> 6;
    int gf = kg % GF, ks = kg / GF;
    int g = gf * 16 + (lane & 15);
    int h0 = ks * 32 + (lane >> 4) * 8;
    ushort v[8];
#pragma unroll
    for (int j = 0; j < 8; ++j) {
        int h = h0 + j;
        v[j] = (g < HH && h < HH) ? f2bf(Uw[g * HH + h]) : (ushort)0;
    }
    *reinterpret_cast<short8*>(Bp + (size_t)idx * 8) = *reinterpret_cast<const short8*>(v);
}

// Vx[b,n,g] = sum_h x[b,n,h]*Vw[g,h] + Vb[g]   (f32, tiny)
__global__ void vx_kernel(const float* __restrict__ x, const float* __restrict__ Vw,
                          const float* __restrict__ Vb, float* __restrict__ Vx) {
    __shared__ float xs[HH];
    int row = blockIdx.x;  // b*N + n
    const float* xr = x + (size_t)row * HH;
    for (int h = threadIdx.x; h < HH; h += 256) xs[h] = xr[h];
    __syncthreads();
    for (int g = threadIdx.x; g < HH; g += 256) {
        const float4* wr = reinterpret_cast<const float4*>(Vw + (size_t)g * HH);
        const float4* xv = reinterpret_cast<const float4*>(xs);
        float s0 = 0.f, s1 = 0.f, s2 = 0.f, s3 = 0.f;
#pragma unroll 5
        for (int k = 0; k < HH / 4; ++k) {
            float4 w = wr[k];
            float4 xx = xv[k];
            s0 += w.x * xx.x; s1 += w.y * xx.y; s2 += w.z * xx.z; s3 += w.w * xx.w;
        }
        Vx[(size_t)row * HH + g] = Vb[g] + s0 + s1 + s2 + s3;
    }
}

// Main: out[m][g] = (e[m,:] @ Uw[g,:]) + Ub[g] + Vx[t][g] + Vx[b*NN+j][g]
// m = ((b*NN+i)*NN+j), t = b*NN+i. BM=64 rows/block, full G per block.
__launch_bounds__(256, 2)
__global__ void gemm_kernel(const float* __restrict__ e, const ushort* __restrict__ Bp,
                            const float* __restrict__ Ub, const float* __restrict__ Vx,
                            float* __restrict__ out) {
    __shared__ ushort Alds[64 * ALD];
    const int tid = threadIdx.x;
    const int lane = tid & 63, wave = tid >> 6;
    const int m0 = blockIdx.x * 64;

    // Stage A: flat coalesced f32 copy of e[m0:m0+64][0:300] -> bf16 LDS [64][ALD]
    const float* eb = e + (size_t)m0 * HH;
    for (int f4 = tid; f4 < (64 * HH) / 4; f4 += 256) {
        int f = f4 * 4;
        int row = f / HH;
        int h = f - row * HH;  // multiple of 4, within row (300 % 4 == 0)
        float4 v = *reinterpret_cast<const float4*>(eb + f);
        ushort4 w;
        w.x = f2bf(v.x); w.y = f2bf(v.y); w.z = f2bf(v.z); w.w = f2bf(v.w);
        *reinterpret_cast<ushort4*>(&Alds[row * ALD + h]) = w;
    }
    // zero-pad h in [300, 320)
    for (int idx = tid; idx < 64 * 10; idx += 256) {
        int row = idx / 10;
        int h = 300 + (idx % 10) * 2;
        *reinterpret_cast<uint*>(&Alds[row * ALD + h]) = 0u;
    }
    __syncthreads();

    float4v acc[GF];
#pragma unroll
    for (int gf = 0; gf < GF; ++gf) acc[gf] = (float4v){0.f, 0.f, 0.f, 0.f};

    const int arow = wave * 16 + (lane & 15);
    const int koff = (lane >> 4) * 8;
    const short8* bp = reinterpret_cast<const short8*>(Bp);

#pragma unroll 1
    for (int ks = 0; ks < KS; ++ks) {
        short8 a = *reinterpret_cast<const short8*>(&Alds[arow * ALD + ks * 32 + koff]);
        short8 bfr[GF];
#pragma unroll
        for (int gf = 0; gf < GF; ++gf)
            bfr[gf] = bp[(ks * GF + gf) * 64 + lane];
#pragma unroll
        for (int gf = 0; gf < GF; ++gf)
            acc[gf] = __builtin_amdgcn_mfma_f32_16x16x32_bf16(a, bfr[gf], acc[gf], 0, 0, 0);
    }

    // Epilogue: + Ub + Vx[i-row] + Vx[j-row], masked store g<300
    const int col = lane & 15;
    const int rg = (lane >> 4) * 4;
#pragma unroll
    for (int r = 0; r < 4; ++r) {
        int m = m0 + wave * 16 + rg + r;
        int j = m % NN;
        int t = m / NN;       // b*NN + i
        int b = t / NN;
        const float* vi = Vx + (size_t)t * HH;
        const float* vj = Vx + (size_t)(b * NN + j) * HH;
        float* orow = out + (size_t)m * HH;
#pragma unroll
        for (int gf = 0; gf < GF; ++gf) {
            int g = gf * 16 + col;
            if (g < HH)
                orow[g] = acc[gf][r] + Ub[g] + vi[g] + vj[g];
        }
    }
}

extern "C" void kernel_launch(void* const* d_in, const int* in_sizes, int n_in,
                              void* d_out, int out_size, void* d_ws, size_t ws_size,
                              hipStream_t stream) {
    const float* x  = (const float*)d_in[0];
    const float* e  = (const float*)d_in[1];
    const float* Uw = (const float*)d_in[2];
    const float* Ub = (const float*)d_in[3];
    const float* Vw = (const float*)d_in[4];
    const float* Vb = (const float*)d_in[5];
    float* out = (float*)d_out;

    ushort* Bp = (ushort*)d_ws;                          // 194,560 B (frag-packed bf16 U_w)
    float*  Vx = (float*)((char*)d_ws + 194560);         // 960,000 B

    pack_u<<<48, 256, 0, stream>>>(Uw, Bp);
    vx_kernel<<<BB * NN, 256, 0, stream>>>(x, Vw, Vb, Vx);
    gemm_kernel<<<2500, 256, 0, stream>>>(e, Bp, Ub, Vx, out);
}

// Round 3
// 174.698 us; speedup vs baseline: 1.3103x; 1.3103x over previous
//
#include <hip/hip_runtime.h>
#include <hip/hip_bf16.h>

#define BB 4
#define NN 200
#define HH 300
#define KS 10   // k-steps of 32 (K padded to 320)
#define GF 19   // g-frags of 16 (G padded to 304)

typedef __attribute__((ext_vector_type(8))) short short8;
typedef __attribute__((ext_vector_type(4))) float float4v;

static __device__ __forceinline__ ushort f2bf(float x) {
    union { float f; uint u; } v; v.f = x;
    uint r = v.u + 0x7FFFu + ((v.u >> 16) & 1u);  // RNE
    return (ushort)(r >> 16);
}

static __device__ __forceinline__ short8 pack8(float4 a, float4 b) {
    short8 r;
    r[0] = (short)f2bf(a.x); r[1] = (short)f2bf(a.y);
    r[2] = (short)f2bf(a.z); r[3] = (short)f2bf(a.w);
    r[4] = (short)f2bf(b.x); r[5] = (short)f2bf(b.y);
    r[6] = (short)f2bf(b.z); r[7] = (short)f2bf(b.w);
    return r;
}

// Pack U_w (g,h) f32 -> bf16 in MFMA B-fragment order:
// Bp[((ks*GF+gf)*64 + lane)*8 + j] = Uw[g= gf*16+(lane&15)][h= ks*32+(lane>>4)*8+j], 0 if OOB
__global__ void pack_u(const float* __restrict__ Uw, ushort* __restrict__ Bp) {
    int idx = blockIdx.x * 256 + threadIdx.x;
    if (idx >= KS * GF * 64) return;
    int lane = idx & 63;
    int kg = idx >> 6;
    int gf = kg % GF, ks = kg / GF;
    int g = gf * 16 + (lane & 15);
    int h0 = ks * 32 + (lane >> 4) * 8;
    ushort v[8];
#pragma unroll
    for (int j = 0; j < 8; ++j) {
        int h = h0 + j;
        v[j] = (g < HH && h < HH) ? f2bf(Uw[g * HH + h]) : (ushort)0;
    }
    *reinterpret_cast<short8*>(Bp + (size_t)idx * 8) = *reinterpret_cast<const short8*>(v);
}

// Vx[b,n,g] = sum_h x[b,n,h]*Vw[g,h] + Vb[g]   (f32, tiny)
__global__ void vx_kernel(const float* __restrict__ x, const float* __restrict__ Vw,
                          const float* __restrict__ Vb, float* __restrict__ Vx) {
    __shared__ float xs[HH];
    int row = blockIdx.x;  // b*N + n
    const float* xr = x + (size_t)row * HH;
    for (int h = threadIdx.x; h < HH; h += 256) xs[h] = xr[h];
    __syncthreads();
    for (int g = threadIdx.x; g < HH; g += 256) {
        const float4* wr = reinterpret_cast<const float4*>(Vw + (size_t)g * HH);
        const float4* xv = reinterpret_cast<const float4*>(xs);
        float s0 = 0.f, s1 = 0.f, s2 = 0.f, s3 = 0.f;
#pragma unroll 5
        for (int k = 0; k < HH / 4; ++k) {
            float4 w = wr[k];
            float4 xx = xv[k];
            s0 += w.x * xx.x; s1 += w.y * xx.y; s2 += w.z * xx.z; s3 += w.w * xx.w;
        }
        Vx[(size_t)row * HH + g] = Vb[g] + s0 + s1 + s2 + s3;
    }
}

// LDS-free GEMM: each wave owns 32 rows (two 16-row MFMA tiles sharing B-frags).
// A straight from global (f32 -> bf16 in reg), B frag-packed in L2, no barriers.
__launch_bounds__(256, 2)
__global__ void gemm_kernel(const float* __restrict__ e, const ushort* __restrict__ Bp,
                            const float* __restrict__ Ub, const float* __restrict__ Vx,
                            float* __restrict__ out) {
    const int tid = threadIdx.x;
    const int lane = tid & 63, wave = tid >> 6;
    const int wt = blockIdx.x * 4 + wave;   // wave-tile id, 0..4999
    const int m0 = wt * 32;
    const int r = lane & 15, q = lane >> 4;
    const int kq = q * 8;

    const float* rowA = e + (size_t)(m0 + r) * HH;
    const float* rowB = e + (size_t)(m0 + 16 + r) * HH;

    const float4 z4 = {0.f, 0.f, 0.f, 0.f};
    // prefetch ks=0 (always fully in-bounds: kq+8 <= 32)
    float4 pa0 = *reinterpret_cast<const float4*>(rowA + kq);
    float4 pa1 = *reinterpret_cast<const float4*>(rowA + kq + 4);
    float4 pb0 = *reinterpret_cast<const float4*>(rowB + kq);
    float4 pb1 = *reinterpret_cast<const float4*>(rowB + kq + 4);

    float4v acc0[GF], acc1[GF];
#pragma unroll
    for (int gf = 0; gf < GF; ++gf) {
        acc0[gf] = (float4v){0.f, 0.f, 0.f, 0.f};
        acc1[gf] = (float4v){0.f, 0.f, 0.f, 0.f};
    }

    const short8* bp = reinterpret_cast<const short8*>(Bp);

#pragma unroll 1
    for (int ks = 0; ks < KS; ++ks) {
        short8 fa = pack8(pa0, pa1);
        short8 fb = pack8(pb0, pb1);

        // prefetch next k-step's A during this step's MFMAs
        if (ks < KS - 1) {
            int kb = (ks + 1) * 32 + kq;
            if (kb + 8 <= HH) {   // true for all lanes when ks+1 <= 8's bulk; lane-varying only at ks+1==9
                pa0 = *reinterpret_cast<const float4*>(rowA + kb);
                pa1 = *reinterpret_cast<const float4*>(rowA + kb + 4);
                pb0 = *reinterpret_cast<const float4*>(rowB + kb);
                pb1 = *reinterpret_cast<const float4*>(rowB + kb + 4);
            } else {
                pa0 = (kb + 4 <= HH) ? *reinterpret_cast<const float4*>(rowA + kb) : z4;
                pb0 = (kb + 4 <= HH) ? *reinterpret_cast<const float4*>(rowB + kb) : z4;
                pa1 = z4;
                pb1 = z4;
            }
        }

        // chunk 1: gf 0..9
        {
            short8 bf[10];
#pragma unroll
            for (int gf = 0; gf < 10; ++gf)
                bf[gf] = bp[(ks * GF + gf) * 64 + lane];
#pragma unroll
            for (int gf = 0; gf < 10; ++gf) {
                acc0[gf] = __builtin_amdgcn_mfma_f32_16x16x32_bf16(fa, bf[gf], acc0[gf], 0, 0, 0);
                acc1[gf] = __builtin_amdgcn_mfma_f32_16x16x32_bf16(fb, bf[gf], acc1[gf], 0, 0, 0);
            }
        }
        // chunk 2: gf 10..18
        {
            short8 bf[9];
#pragma unroll
            for (int gf = 0; gf < 9; ++gf)
                bf[gf] = bp[(ks * GF + 10 + gf) * 64 + lane];
#pragma unroll
            for (int gf = 0; gf < 9; ++gf) {
                acc0[10 + gf] = __builtin_amdgcn_mfma_f32_16x16x32_bf16(fa, bf[gf], acc0[10 + gf], 0, 0, 0);
                acc1[10 + gf] = __builtin_amdgcn_mfma_f32_16x16x32_bf16(fb, bf[gf], acc1[10 + gf], 0, 0, 0);
            }
        }
    }

    // Epilogue: + Ub + Vx[i-row] + Vx[j-row], masked store g<300
    const int col = lane & 15;
    const int rg = q * 4;
#pragma unroll
    for (int t2 = 0; t2 < 2; ++t2) {
        const float4v* acc = t2 ? acc1 : acc0;
        const int mt = m0 + t2 * 16;
#pragma unroll
        for (int r4 = 0; r4 < 4; ++r4) {
            int m = mt + rg + r4;
            int j = m % NN;
            int t = m / NN;       // b*NN + i
            int b = t / NN;
            const float* vi = Vx + (size_t)t * HH;
            const float* vj = Vx + (size_t)(b * NN + j) * HH;
            float* orow = out + (size_t)m * HH;
#pragma unroll
            for (int gf = 0; gf < GF; ++gf) {
                int g = gf * 16 + col;
                if (g < HH)
                    orow[g] = acc[gf][r4] + Ub[g] + vi[g] + vj[g];
            }
        }
    }
}

extern "C" void kernel_launch(void* const* d_in, const int* in_sizes, int n_in,
                              void* d_out, int out_size, void* d_ws, size_t ws_size,
                              hipStream_t stream) {
    const float* x  = (const float*)d_in[0];
    const float* e  = (const float*)d_in[1];
    const float* Uw = (const float*)d_in[2];
    const float* Ub = (const float*)d_in[3];
    const float* Vw = (const float*)d_in[4];
    const float* Vb = (const float*)d_in[5];
    float* out = (float*)d_out;

    ushort* Bp = (ushort*)d_ws;                          // 194,560 B (frag-packed bf16 U_w)
    float*  Vx = (float*)((char*)d_ws + 194560);         // 960,000 B

    pack_u<<<48, 256, 0, stream>>>(Uw, Bp);
    vx_kernel<<<BB * NN, 256, 0, stream>>>(x, Vw, Vb, Vx);
    gemm_kernel<<<1250, 256, 0, stream>>>(e, Bp, Ub, Vx, out);
}